// Round 4
// baseline (308.844 us; speedup 1.0000x reference)
//
#include <hip/hip_runtime.h>

typedef __attribute__((ext_vector_type(8))) short short8;
typedef __attribute__((ext_vector_type(4))) float f32x4;

#define NTOK   8192
#define DDIM   1024
#define ENUM   16
#define FDIM   768
#define NSLOT  16384

// ---------- ws layout (bytes) ----------
#define WS_TOPK_IDX 0           // int[16384]
#define WS_TOPK_W   65536       // float[16384]
#define WS_ROWS     131072      // int[16384]
#define WS_ROW_OF   196608      // int[16384]
#define WS_COUNTS   262144      // int[16]
#define WS_PROB     262208      // float[16]
#define WS_OFFSETS  262272      // int[17]
#define WS_XBF      1048576ull                      // bf16[8192][1024]   16 MB
#define WS_H        (WS_XBF + 16777216ull)          // bf16[16384][768]   24 MB
#define WS_WGT      (WS_H + 25165824ull)            // bf16[E][F][D]      24 MB
#define WS_WUT      (WS_WGT + 25165824ull)          // bf16[E][F][D]      24 MB
#define WS_WDT      (WS_WUT + 25165824ull)          // bf16[E][D][F]      24 MB
#define WS_O        (WS_WDT + 25165824ull)          // bf16[16384][1024]  32 MB (optional)
#define WS_NEED_O   (WS_O + 33554432ull)

__device__ __forceinline__ unsigned short f2bf(float f) {
  union { float f; unsigned int u; } v; v.f = f;
  unsigned int r = v.u + 0x7fffu + ((v.u >> 16) & 1u);
  return (unsigned short)(r >> 16);
}
__device__ __forceinline__ float bf2f(unsigned short s) {
  union { unsigned int u; float f; } v; v.u = ((unsigned int)s) << 16;
  return v.f;
}

__device__ __forceinline__ void gld16(const void* g, void* l) {
  __builtin_amdgcn_global_load_lds((const __attribute__((address_space(1))) unsigned int*)g,
                                   (__attribute__((address_space(3))) unsigned int*)l, 16, 0, 0);
}

// ---------------- 1. hidden fp32 -> bf16 ----------------
__global__ void k_convert_x(const float* __restrict__ x, unsigned short* __restrict__ xb) {
  int i = blockIdx.x * blockDim.x + threadIdx.x;
  float4 v = ((const float4*)x)[i];
  ushort4 o;
  o.x = f2bf(v.x); o.y = f2bf(v.y); o.z = f2bf(v.z); o.w = f2bf(v.w);
  ((ushort4*)xb)[i] = o;
}

// ---------------- 1b. weight transpose+convert: WT[e][c][r] = bf16(W[e][r][c]) ----------------
__global__ __launch_bounds__(256) void k_wt(const float* __restrict__ W,
                                            unsigned short* __restrict__ WT,
                                            int R, int C) {
  __shared__ float t[64][68];
  int e = blockIdx.z;
  int r0 = blockIdx.y * 64, c0 = blockIdx.x * 64;
  int tid = threadIdx.x;
  int rr = tid >> 2, cc = (tid & 3) * 16;
  const float* src = W + (size_t)e * R * C + (size_t)(r0 + rr) * C + c0 + cc;
  float4 v0 = *(const float4*)(src);
  float4 v1 = *(const float4*)(src + 4);
  float4 v2 = *(const float4*)(src + 8);
  float4 v3 = *(const float4*)(src + 12);
  *(float4*)&t[rr][cc]      = v0;
  *(float4*)&t[rr][cc + 4]  = v1;
  *(float4*)&t[rr][cc + 8]  = v2;
  *(float4*)&t[rr][cc + 12] = v3;
  __syncthreads();
  int fr = tid >> 2, dd = (tid & 3) * 16;
  union { unsigned short s[16]; uint4 v[2]; } o;
  #pragma unroll
  for (int j = 0; j < 16; j++) o.s[j] = f2bf(t[dd + j][fr]);
  unsigned short* dst = WT + (size_t)e * C * R + (size_t)(c0 + fr) * R + r0 + dd;
  *(uint4*)dst = o.v[0];
  *((uint4*)dst + 1) = o.v[1];
}

// ---------------- 2. router ----------------
__global__ __launch_bounds__(256) void k_router(
    const float* __restrict__ X, const float* __restrict__ Wr,
    int* __restrict__ topk_idx, float* __restrict__ topk_w,
    int* __restrict__ counts, float* __restrict__ prob_sum)
{
  int tid = threadIdx.x, lane = tid & 63, wid = tid >> 6;
  int wave_global = blockIdx.x * 4 + wid;
  int q = lane >> 4, e = lane & 15;
  float pacc = 0.f; int cacc = 0;

  for (int i = 0; i < 4; i++) {
    int t = wave_global * 4 + i;
    const float* x = X + (size_t)t * DDIM + q * 256;
    const float* w = Wr + q * 256 * ENUM + e;
    double a0 = 0.0, a1 = 0.0;
    #pragma unroll 4
    for (int j = 0; j < 256; j += 2) {
      a0 += (double)x[j] * (double)w[j * ENUM];
      a1 += (double)x[j + 1] * (double)w[(j + 1) * ENUM];
    }
    double acc = a0 + a1;
    acc += __shfl_xor(acc, 16, 64);
    acc += __shfl_xor(acc, 32, 64);
    float logit = (float)acc;

    float m = logit;
    for (int d = 1; d < 16; d <<= 1) m = fmaxf(m, __shfl_xor(m, d, 64));
    float p = expf(logit - m);
    float s = p;
    for (int d = 1; d < 16; d <<= 1) s += __shfl_xor(s, d, 64);
    p = p / s;

    float p1 = p; int e1 = e;
    for (int d = 1; d < 16; d <<= 1) {
      float op = __shfl_xor(p1, d, 64); int oe = __shfl_xor(e1, d, 64);
      if (op > p1 || (op == p1 && oe < e1)) { p1 = op; e1 = oe; }
    }
    float px = (e == e1) ? -1.f : p;
    float p2 = px; int e2 = e;
    for (int d = 1; d < 16; d <<= 1) {
      float op = __shfl_xor(p2, d, 64); int oe = __shfl_xor(e2, d, 64);
      if (op > p2 || (op == p2 && oe < e2)) { p2 = op; e2 = oe; }
    }
    float den = fmaxf(p1 + p2, 1e-9f);
    if (lane == 0) {
      topk_idx[2 * t]     = e1; topk_idx[2 * t + 1] = e2;
      topk_w[2 * t]       = p1 / den; topk_w[2 * t + 1] = p2 / den;
    }
    if (lane < 16) { pacc += p; cacc += (e1 == e) + (e2 == e); }
  }
  __shared__ float sp[16]; __shared__ int sc[16];
  if (tid < 16) { sp[tid] = 0.f; sc[tid] = 0; }
  __syncthreads();
  if (lane < 16) { atomicAdd(&sp[e], pacc); atomicAdd(&sc[e], cacc); }
  __syncthreads();
  if (tid < 16) { atomicAdd(&prob_sum[tid], sp[tid]); atomicAdd(&counts[tid], sc[tid]); }
}

// ---------------- 3. deterministic per-expert slot lists ----------------
__global__ __launch_bounds__(256) void k_build_lists(
    const int* __restrict__ topk_idx, const int* __restrict__ counts,
    int* __restrict__ offsets, int* __restrict__ rows, int* __restrict__ row_of)
{
  int e = blockIdx.x;
  int base = 0;
  for (int i = 0; i < e; i++) base += counts[i];
  if (threadIdx.x == 0) {
    offsets[e] = base;
    if (e == 15) offsets[16] = base + counts[15];
  }
  __shared__ int wave_tot[4];
  int lane = threadIdx.x & 63, wid = threadIdx.x >> 6;
  int running = 0;
  for (int chunk = 0; chunk < NSLOT; chunk += 256) {
    int s = chunk + threadIdx.x;
    bool match = (topk_idx[s] == e);
    unsigned long long mask = __ballot(match);
    int wpre = __popcll(mask & ((1ull << lane) - 1ull));
    if (lane == 0) wave_tot[wid] = __popcll(mask);
    __syncthreads();
    int prefix = running;
    for (int w = 0; w < wid; w++) prefix += wave_tot[w];
    if (match) { int pos = base + prefix + wpre; rows[pos] = s; row_of[s] = pos; }
    running += wave_tot[0] + wave_tot[1] + wave_tot[2] + wave_tot[3];
    __syncthreads();
  }
}

// ---------------- 4. fused gate+up grouped GEMM ----------------
// depth-2 counted-vmcnt pipeline, triple-buffered LDS, one raw barrier/K-step.
// tile 128(M) x 128(N of F) x 64(K); 8 waves (2m x 4n); wave tile 64x32
__global__ __launch_bounds__(512) void k_gateup(
    const unsigned short* __restrict__ Xbf, const unsigned short* __restrict__ WgT,
    const unsigned short* __restrict__ WuT, const int* __restrict__ counts,
    const int* __restrict__ offsets, const int* __restrict__ rows,
    unsigned short* __restrict__ H)
{
  const int id = blockIdx.x;
  const int xcd = id & 7;
  const int within = id >> 3;                // 0..767
  const int e = xcd * 2 + (within >= 384);
  const int rem = within - (within >= 384 ? 384 : 0);
  const int mt = rem / 6;
  const int nt = rem - mt * 6;

  const int cnt = counts[e];
  if (mt * 128 >= cnt) return;
  const int base = offsets[e];

  #define GU_BUF 16384
  __shared__ __align__(16) unsigned char sA [3 * GU_BUF];
  __shared__ __align__(16) unsigned char sBg[3 * GU_BUF];
  __shared__ __align__(16) unsigned char sBu[3 * GU_BUF];
  __shared__ int sTok[128];

  const int tid = threadIdx.x;
  const int lane = tid & 63;
  const int wid = tid >> 6;
  const int wm = wid >> 2, wn = wid & 3;
  const int q = lane >> 4, c = lane & 15;

  if (tid < 128) {
    int r = mt * 128 + tid;
    if (r >= cnt) r = cnt - 1;
    sTok[tid] = rows[base + r];
  }
  __syncthreads();

  const int rstg0 = wid * 16 + (lane >> 3);
  const int rstg1 = rstg0 + 8;
  const int colSw = (((lane & 7) << 4) ^ ((lane >> 3) << 4)) >> 1;  // ushorts
  const unsigned short* tokp0 = Xbf + (size_t)(sTok[rstg0] >> 1) * DDIM + colSw;
  const unsigned short* tokp1 = Xbf + (size_t)(sTok[rstg1] >> 1) * DDIM + colSw;
  const unsigned short* wg0 = WgT + ((size_t)e * FDIM + nt * 128 + rstg0) * DDIM + colSw;
  const unsigned short* wg1 = WgT + ((size_t)e * FDIM + nt * 128 + rstg1) * DDIM + colSw;
  const unsigned short* wu0 = WuT + ((size_t)e * FDIM + nt * 128 + rstg0) * DDIM + colSw;
  const unsigned short* wu1 = WuT + ((size_t)e * FDIM + nt * 128 + rstg1) * DDIM + colSw;
  const int woff = wid * 2048;

  f32x4 accg[4][2], accu[4][2];
  #pragma unroll
  for (int i = 0; i < 4; i++)
    #pragma unroll
    for (int j = 0; j < 2; j++) { accg[i][j] = (f32x4)(0.f); accu[i][j] = (f32x4)(0.f); }

  // stage(kt -> buffer b): 6 gld16 per wave
  #define GU_STAGE(kt_, b_) do {                                      \
    const int ko_ = (kt_) * 64;                                       \
    unsigned char* a_ = sA  + (b_) * GU_BUF + woff;                   \
    unsigned char* g_ = sBg + (b_) * GU_BUF + woff;                   \
    unsigned char* u_ = sBu + (b_) * GU_BUF + woff;                   \
    gld16(tokp0 + ko_, a_);  gld16(tokp1 + ko_, a_ + 1024);           \
    gld16(wg0 + ko_,   g_);  gld16(wg1 + ko_,   g_ + 1024);           \
    gld16(wu0 + ko_,   u_);  gld16(wu1 + ko_,   u_ + 1024);           \
  } while (0)

  GU_STAGE(0, 0);
  GU_STAGE(1, 1);

  int cur = 0, nxt = 2;
  for (int kt = 0; kt < DDIM / 64; kt++) {
    // own stage(kt) done; stage(kt+1) stays in flight (counted wait)
    if (kt == DDIM / 64 - 1) asm volatile("s_waitcnt vmcnt(0)" ::: "memory");
    else                     asm volatile("s_waitcnt vmcnt(6)" ::: "memory");
    __builtin_amdgcn_s_barrier();            // all waves: kt ready, kt-1 reads done
    if (kt + 2 < DDIM / 64) GU_STAGE(kt + 2, nxt);

    const unsigned char* bA = sA  + cur * GU_BUF;
    const unsigned char* bG = sBg + cur * GU_BUF;
    const unsigned char* bU = sBu + cur * GU_BUF;
    __builtin_amdgcn_s_setprio(1);
    #pragma unroll
    for (int kk = 0; kk < 2; kk++) {
      short8 af[4];
      #pragma unroll
      for (int mf = 0; mf < 4; mf++) {
        int row = wm * 64 + mf * 16 + c;
        af[mf] = *(const short8*)(bA + ((row * 128 + kk * 64 + q * 16) ^ ((row & 7) << 4)));
      }
      #pragma unroll
      for (int nf = 0; nf < 2; nf++) {
        int col = wn * 32 + nf * 16 + c;
        int b = (col * 128 + kk * 64 + q * 16) ^ ((col & 7) << 4);
        short8 bg = *(const short8*)(bG + b);
        short8 bu = *(const short8*)(bU + b);
        #pragma unroll
        for (int mf = 0; mf < 4; mf++) {
          accg[mf][nf] = __builtin_amdgcn_mfma_f32_16x16x32_bf16(af[mf], bg, accg[mf][nf], 0, 0, 0);
          accu[mf][nf] = __builtin_amdgcn_mfma_f32_16x16x32_bf16(af[mf], bu, accu[mf][nf], 0, 0, 0);
        }
      }
    }
    __builtin_amdgcn_s_setprio(0);
    cur = (cur == 2) ? 0 : cur + 1;
    nxt = (nxt == 2) ? 0 : nxt + 1;
  }

  #pragma unroll
  for (int mf = 0; mf < 4; mf++)
    #pragma unroll
    for (int nf = 0; nf < 2; nf++)
      #pragma unroll
      for (int r = 0; r < 4; r++) {
        int row = wm * 64 + mf * 16 + q * 4 + r;
        int gr = mt * 128 + row;
        if (gr < cnt) {
          int col = wn * 32 + nf * 16 + c;
          float g = accg[mf][nf][r], u = accu[mf][nf][r];
          float sv = g / (1.0f + __expf(-g));
          H[(size_t)(base + gr) * FDIM + nt * 128 + col] = f2bf(sv * u);
        }
      }
}

// ---------------- 5. down grouped GEMM (same pipeline) ----------------
// MODE 0: store bf16 O;  MODE 1: weighted atomicAdd into out (out pre-zeroed)
template <int MODE>
__global__ __launch_bounds__(512) void k_down(
    const unsigned short* __restrict__ H, const unsigned short* __restrict__ WdT,
    const int* __restrict__ counts, const int* __restrict__ offsets,
    const int* __restrict__ rows, const float* __restrict__ topk_w,
    unsigned short* __restrict__ O, float* __restrict__ out)
{
  const int id = blockIdx.x;
  const int xcd = id & 7;
  const int within = id >> 3;                // 0..1023
  const int e = xcd * 2 + (within >> 9);
  const int rem = within & 511;
  const int mt = rem >> 3;
  const int nt = rem & 7;

  const int cnt = counts[e];
  if (mt * 128 >= cnt) return;
  const int base = offsets[e];

  #define DN_BUF 16384
  __shared__ __align__(16) unsigned char sA[3 * DN_BUF];
  __shared__ __align__(16) unsigned char sB[3 * DN_BUF];
  __shared__ int sTk[128];
  __shared__ float sW[128];

  const int tid = threadIdx.x;
  const int lane = tid & 63;
  const int wid = tid >> 6;
  const int wm = wid >> 2, wn = wid & 3;
  const int q = lane >> 4, c = lane & 15;

  if (MODE == 1 && tid < 128) {
    int r = mt * 128 + tid;
    if (r >= cnt) r = cnt - 1;
    int s = rows[base + r];
    sTk[tid] = s >> 1;
    sW[tid] = topk_w[s];
  }
  if (MODE == 1) __syncthreads();

  const int rstg0 = wid * 16 + (lane >> 3);
  const int rstg1 = rstg0 + 8;
  const int colSw = (((lane & 7) << 4) ^ ((lane >> 3) << 4)) >> 1;
  int ga0 = base + mt * 128 + rstg0; if (ga0 > NSLOT - 1) ga0 = NSLOT - 1;
  int ga1 = base + mt * 128 + rstg1; if (ga1 > NSLOT - 1) ga1 = NSLOT - 1;
  const unsigned short* hp0 = H + (size_t)ga0 * FDIM + colSw;
  const unsigned short* hp1 = H + (size_t)ga1 * FDIM + colSw;
  const unsigned short* wd0 = WdT + ((size_t)e * DDIM + nt * 128 + rstg0) * FDIM + colSw;
  const unsigned short* wd1 = WdT + ((size_t)e * DDIM + nt * 128 + rstg1) * FDIM + colSw;
  const int woff = wid * 2048;

  f32x4 acc[4][2];
  #pragma unroll
  for (int i = 0; i < 4; i++)
    #pragma unroll
    for (int j = 0; j < 2; j++) acc[i][j] = (f32x4)(0.f);

  #define DN_STAGE(kt_, b_) do {                                      \
    const int ko_ = (kt_) * 64;                                       \
    unsigned char* a_ = sA + (b_) * DN_BUF + woff;                    \
    unsigned char* w_ = sB + (b_) * DN_BUF + woff;                    \
    gld16(hp0 + ko_, a_); gld16(hp1 + ko_, a_ + 1024);                \
    gld16(wd0 + ko_, w_); gld16(wd1 + ko_, w_ + 1024);                \
  } while (0)

  DN_STAGE(0, 0);
  DN_STAGE(1, 1);

  int cur = 0, nxt = 2;
  for (int kt = 0; kt < FDIM / 64; kt++) {
    if (kt == FDIM / 64 - 1) asm volatile("s_waitcnt vmcnt(0)" ::: "memory");
    else                     asm volatile("s_waitcnt vmcnt(4)" ::: "memory");
    __builtin_amdgcn_s_barrier();
    if (kt + 2 < FDIM / 64) DN_STAGE(kt + 2, nxt);

    const unsigned char* bA = sA + cur * DN_BUF;
    const unsigned char* bB = sB + cur * DN_BUF;
    __builtin_amdgcn_s_setprio(1);
    #pragma unroll
    for (int kk = 0; kk < 2; kk++) {
      short8 af[4];
      #pragma unroll
      for (int mf = 0; mf < 4; mf++) {
        int row = wm * 64 + mf * 16 + c;
        af[mf] = *(const short8*)(bA + ((row * 128 + kk * 64 + q * 16) ^ ((row & 7) << 4)));
      }
      #pragma unroll
      for (int nf = 0; nf < 2; nf++) {
        int col = wn * 32 + nf * 16 + c;
        short8 bf = *(const short8*)(bB + ((col * 128 + kk * 64 + q * 16) ^ ((col & 7) << 4)));
        #pragma unroll
        for (int mf = 0; mf < 4; mf++)
          acc[mf][nf] = __builtin_amdgcn_mfma_f32_16x16x32_bf16(af[mf], bf, acc[mf][nf], 0, 0, 0);
      }
    }
    __builtin_amdgcn_s_setprio(0);
    cur = (cur == 2) ? 0 : cur + 1;
    nxt = (nxt == 2) ? 0 : nxt + 1;
  }

  #pragma unroll
  for (int mf = 0; mf < 4; mf++)
    #pragma unroll
    for (int nf = 0; nf < 2; nf++)
      #pragma unroll
      for (int r = 0; r < 4; r++) {
        int row = wm * 64 + mf * 16 + q * 4 + r;
        int gr = mt * 128 + row;
        if (gr < cnt) {
          int col = wn * 32 + nf * 16 + c;
          if (MODE == 0) {
            O[(size_t)(base + gr) * DDIM + nt * 128 + col] = f2bf(acc[mf][nf][r]);
          } else {
            atomicAdd(&out[(size_t)sTk[row] * DDIM + nt * 128 + col], sW[row] * acc[mf][nf][r]);
          }
        }
      }
}

// ---------------- 6. combine top-2 (MODE 0 only) ----------------
__global__ __launch_bounds__(128) void k_combine(
    const unsigned short* __restrict__ O, const int* __restrict__ row_of,
    const float* __restrict__ topk_w, float* __restrict__ out)
{
  int t = blockIdx.x;
  int r0 = row_of[2 * t], r1 = row_of[2 * t + 1];
  float w0 = topk_w[2 * t], w1 = topk_w[2 * t + 1];
  int d = threadIdx.x * 8;
  short8 a = *(const short8*)(O + (size_t)r0 * DDIM + d);
  short8 b = *(const short8*)(O + (size_t)r1 * DDIM + d);
  float4 o0, o1;
  #pragma unroll
  for (int j = 0; j < 8; j++) {
    float r = w0 * bf2f((unsigned short)a[j]) + w1 * bf2f((unsigned short)b[j]);
    if (j < 4) ((float*)&o0)[j] = r; else ((float*)&o1)[j - 4] = r;
  }
  *(float4*)(out + (size_t)t * DDIM + d) = o0;
  *(float4*)(out + (size_t)t * DDIM + d + 4) = o1;
}

// ---------------- 7. aux loss ----------------
__global__ void k_aux(const int* __restrict__ counts, const float* __restrict__ prob_sum,
                      float* __restrict__ out_aux) {
  if (threadIdx.x == 0) {
    float s = 0.f;
    for (int e = 0; e < ENUM; e++)
      s += ((float)counts[e] / (float)NTOK) * (prob_sum[e] / (float)NTOK);
    out_aux[0] = 0.001f * (float)ENUM * s;
  }
}

extern "C" void kernel_launch(void* const* d_in, const int* in_sizes, int n_in,
                              void* d_out, int out_size, void* d_ws, size_t ws_size,
                              hipStream_t stream) {
  const float* X  = (const float*)d_in[0];
  const float* Wg = (const float*)d_in[1];
  const float* Wu = (const float*)d_in[2];
  const float* Wd = (const float*)d_in[3];
  const float* Wr = (const float*)d_in[4];
  float* out = (float*)d_out;

  char* ws = (char*)d_ws;
  int*   topk_idx = (int*)(ws + WS_TOPK_IDX);
  float* topk_w   = (float*)(ws + WS_TOPK_W);
  int*   rows     = (int*)(ws + WS_ROWS);
  int*   row_of   = (int*)(ws + WS_ROW_OF);
  int*   counts   = (int*)(ws + WS_COUNTS);
  float* prob_sum = (float*)(ws + WS_PROB);
  int*   offsets  = (int*)(ws + WS_OFFSETS);
  unsigned short* Xbf = (unsigned short*)(ws + WS_XBF);
  unsigned short* H   = (unsigned short*)(ws + WS_H);
  unsigned short* WgT = (unsigned short*)(ws + WS_WGT);
  unsigned short* WuT = (unsigned short*)(ws + WS_WUT);
  unsigned short* WdT = (unsigned short*)(ws + WS_WDT);
  unsigned short* O   = (unsigned short*)(ws + WS_O);

  const bool useO = (ws_size >= WS_NEED_O);

  hipMemsetAsync(ws + WS_COUNTS, 0, 128, stream);
  if (!useO) hipMemsetAsync(d_out, 0, (size_t)out_size * 4, stream);

  k_convert_x<<<8192, 256, 0, stream>>>(X, Xbf);
  k_wt<<<dim3(FDIM / 64, DDIM / 64, ENUM), 256, 0, stream>>>(Wg, WgT, DDIM, FDIM);
  k_wt<<<dim3(FDIM / 64, DDIM / 64, ENUM), 256, 0, stream>>>(Wu, WuT, DDIM, FDIM);
  k_wt<<<dim3(DDIM / 64, FDIM / 64, ENUM), 256, 0, stream>>>(Wd, WdT, FDIM, DDIM);
  k_router<<<512, 256, 0, stream>>>(X, Wr, topk_idx, topk_w, counts, prob_sum);
  k_build_lists<<<16, 256, 0, stream>>>(topk_idx, counts, offsets, rows, row_of);
  k_gateup<<<6144, 512, 0, stream>>>(Xbf, WgT, WuT, counts, offsets, rows, H);
  if (useO) {
    k_down<0><<<8192, 512, 0, stream>>>(H, WdT, counts, offsets, rows, topk_w, O, out);
    k_combine<<<8192, 128, 0, stream>>>(O, row_of, topk_w, out);
  } else {
    k_down<1><<<8192, 512, 0, stream>>>(H, WdT, counts, offsets, rows, topk_w, O, out);
  }
  k_aux<<<1, 64, 0, stream>>>(counts, prob_sum, out + (size_t)NTOK * DDIM);
}

// Round 5
// 291.731 us; speedup vs baseline: 1.0587x; 1.0587x over previous
//
#include <hip/hip_runtime.h>

typedef __attribute__((ext_vector_type(8))) short short8;
typedef __attribute__((ext_vector_type(4))) float f32x4;

#define NTOK   8192
#define DDIM   1024
#define ENUM   16
#define FDIM   768
#define NSLOT  16384

// ---------- ws layout (bytes) ----------
#define WS_TOPK_IDX 0           // int[16384]
#define WS_TOPK_W   65536       // float[16384]
#define WS_ROWS     131072      // int[16384]
#define WS_ROW_OF   196608      // int[16384]
#define WS_COUNTS   262144      // int[16]
#define WS_PROB     262208      // float[16]
#define WS_OFFSETS  262272      // int[17]
#define WS_XBF      1048576ull                      // bf16[8192][1024]   16 MB
#define WS_H        (WS_XBF + 16777216ull)          // bf16[16384][768]   24 MB
#define WS_WGT      (WS_H + 25165824ull)            // bf16[E][F][D]      24 MB
#define WS_WUT      (WS_WGT + 25165824ull)          // bf16[E][F][D]      24 MB
#define WS_WDT      (WS_WUT + 25165824ull)          // bf16[E][D][F]      24 MB
#define WS_O        (WS_WDT + 25165824ull)          // bf16[16384][1024]  32 MB (optional)
#define WS_NEED_O   (WS_O + 33554432ull)

__device__ __forceinline__ unsigned short f2bf(float f) {
  union { float f; unsigned int u; } v; v.f = f;
  unsigned int r = v.u + 0x7fffu + ((v.u >> 16) & 1u);
  return (unsigned short)(r >> 16);
}
__device__ __forceinline__ float bf2f(unsigned short s) {
  union { unsigned int u; float f; } v; v.u = ((unsigned int)s) << 16;
  return v.f;
}

__device__ __forceinline__ void gld16(const void* g, void* l) {
  __builtin_amdgcn_global_load_lds((const __attribute__((address_space(1))) unsigned int*)g,
                                   (__attribute__((address_space(3))) unsigned int*)l, 16, 0, 0);
}

// ---------------- 1. hidden fp32 -> bf16 ----------------
__global__ void k_convert_x(const float* __restrict__ x, unsigned short* __restrict__ xb) {
  int i = blockIdx.x * blockDim.x + threadIdx.x;
  float4 v = ((const float4*)x)[i];
  ushort4 o;
  o.x = f2bf(v.x); o.y = f2bf(v.y); o.z = f2bf(v.z); o.w = f2bf(v.w);
  ((ushort4*)xb)[i] = o;
}

// ---------------- 1b. weight transpose+convert: WT[e][c][r] = bf16(W[e][r][c]) ----------------
__global__ __launch_bounds__(256) void k_wt(const float* __restrict__ W,
                                            unsigned short* __restrict__ WT,
                                            int R, int C) {
  __shared__ float t[64][68];
  int e = blockIdx.z;
  int r0 = blockIdx.y * 64, c0 = blockIdx.x * 64;
  int tid = threadIdx.x;
  int rr = tid >> 2, cc = (tid & 3) * 16;
  const float* src = W + (size_t)e * R * C + (size_t)(r0 + rr) * C + c0 + cc;
  float4 v0 = *(const float4*)(src);
  float4 v1 = *(const float4*)(src + 4);
  float4 v2 = *(const float4*)(src + 8);
  float4 v3 = *(const float4*)(src + 12);
  *(float4*)&t[rr][cc]      = v0;
  *(float4*)&t[rr][cc + 4]  = v1;
  *(float4*)&t[rr][cc + 8]  = v2;
  *(float4*)&t[rr][cc + 12] = v3;
  __syncthreads();
  int fr = tid >> 2, dd = (tid & 3) * 16;
  union { unsigned short s[16]; uint4 v[2]; } o;
  #pragma unroll
  for (int j = 0; j < 16; j++) o.s[j] = f2bf(t[dd + j][fr]);
  unsigned short* dst = WT + (size_t)e * C * R + (size_t)(c0 + fr) * R + r0 + dd;
  *(uint4*)dst = o.v[0];
  *((uint4*)dst + 1) = o.v[1];
}

// ---------------- 2. router ----------------
__global__ __launch_bounds__(256) void k_router(
    const float* __restrict__ X, const float* __restrict__ Wr,
    int* __restrict__ topk_idx, float* __restrict__ topk_w,
    int* __restrict__ counts, float* __restrict__ prob_sum)
{
  int tid = threadIdx.x, lane = tid & 63, wid = tid >> 6;
  int wave_global = blockIdx.x * 4 + wid;
  int q = lane >> 4, e = lane & 15;
  float pacc = 0.f; int cacc = 0;

  for (int i = 0; i < 4; i++) {
    int t = wave_global * 4 + i;
    const float* x = X + (size_t)t * DDIM + q * 256;
    const float* w = Wr + q * 256 * ENUM + e;
    double a0 = 0.0, a1 = 0.0;
    #pragma unroll 4
    for (int j = 0; j < 256; j += 2) {
      a0 += (double)x[j] * (double)w[j * ENUM];
      a1 += (double)x[j + 1] * (double)w[(j + 1) * ENUM];
    }
    double acc = a0 + a1;
    acc += __shfl_xor(acc, 16, 64);
    acc += __shfl_xor(acc, 32, 64);
    float logit = (float)acc;

    float m = logit;
    for (int d = 1; d < 16; d <<= 1) m = fmaxf(m, __shfl_xor(m, d, 64));
    float p = expf(logit - m);
    float s = p;
    for (int d = 1; d < 16; d <<= 1) s += __shfl_xor(s, d, 64);
    p = p / s;

    float p1 = p; int e1 = e;
    for (int d = 1; d < 16; d <<= 1) {
      float op = __shfl_xor(p1, d, 64); int oe = __shfl_xor(e1, d, 64);
      if (op > p1 || (op == p1 && oe < e1)) { p1 = op; e1 = oe; }
    }
    float px = (e == e1) ? -1.f : p;
    float p2 = px; int e2 = e;
    for (int d = 1; d < 16; d <<= 1) {
      float op = __shfl_xor(p2, d, 64); int oe = __shfl_xor(e2, d, 64);
      if (op > p2 || (op == p2 && oe < e2)) { p2 = op; e2 = oe; }
    }
    float den = fmaxf(p1 + p2, 1e-9f);
    if (lane == 0) {
      topk_idx[2 * t]     = e1; topk_idx[2 * t + 1] = e2;
      topk_w[2 * t]       = p1 / den; topk_w[2 * t + 1] = p2 / den;
    }
    if (lane < 16) { pacc += p; cacc += (e1 == e) + (e2 == e); }
  }
  __shared__ float sp[16]; __shared__ int sc[16];
  if (tid < 16) { sp[tid] = 0.f; sc[tid] = 0; }
  __syncthreads();
  if (lane < 16) { atomicAdd(&sp[e], pacc); atomicAdd(&sc[e], cacc); }
  __syncthreads();
  if (tid < 16) { atomicAdd(&prob_sum[tid], sp[tid]); atomicAdd(&counts[tid], sc[tid]); }
}

// ---------------- 3. deterministic per-expert slot lists ----------------
__global__ __launch_bounds__(256) void k_build_lists(
    const int* __restrict__ topk_idx, const int* __restrict__ counts,
    int* __restrict__ offsets, int* __restrict__ rows, int* __restrict__ row_of)
{
  int e = blockIdx.x;
  int base = 0;
  for (int i = 0; i < e; i++) base += counts[i];
  if (threadIdx.x == 0) {
    offsets[e] = base;
    if (e == 15) offsets[16] = base + counts[15];
  }
  __shared__ int wave_tot[4];
  int lane = threadIdx.x & 63, wid = threadIdx.x >> 6;
  int running = 0;
  for (int chunk = 0; chunk < NSLOT; chunk += 256) {
    int s = chunk + threadIdx.x;
    bool match = (topk_idx[s] == e);
    unsigned long long mask = __ballot(match);
    int wpre = __popcll(mask & ((1ull << lane) - 1ull));
    if (lane == 0) wave_tot[wid] = __popcll(mask);
    __syncthreads();
    int prefix = running;
    for (int w = 0; w < wid; w++) prefix += wave_tot[w];
    if (match) { int pos = base + prefix + wpre; rows[pos] = s; row_of[s] = pos; }
    running += wave_tot[0] + wave_tot[1] + wave_tot[2] + wave_tot[3];
    __syncthreads();
  }
}

// ---------------- 4. fused gate+up grouped GEMM ----------------
// tile 256(M) x 128(N of F) x 64(K); 8 waves (4m x 2n); wave tile 64x64.
// dbuf + counted-vmcnt two-barrier schedule. mt_max=8 (cnt<=2048; actual ~1024).
__global__ __launch_bounds__(512) void k_gateup(
    const unsigned short* __restrict__ Xbf, const unsigned short* __restrict__ WgT,
    const unsigned short* __restrict__ WuT, const int* __restrict__ counts,
    const int* __restrict__ offsets, const int* __restrict__ rows,
    unsigned short* __restrict__ H)
{
  const int id = blockIdx.x;
  const int xcd = id & 7;
  const int within = id >> 3;                // 0..95
  const int e = xcd * 2 + (within >= 48);
  const int rem = within - (within >= 48 ? 48 : 0);  // 0..47
  const int mt = rem / 6;                    // 0..7
  const int nt = rem - mt * 6;               // 0..5

  const int cnt = counts[e];
  if (mt * 256 >= cnt) return;
  const int base = offsets[e];

  __shared__ __align__(16) unsigned char sA [2][256 * 64 * 2];  // 32KB x2
  __shared__ __align__(16) unsigned char sBg[2][128 * 64 * 2];  // 16KB x2
  __shared__ __align__(16) unsigned char sBu[2][128 * 64 * 2];  // 16KB x2
  __shared__ int sTok[256];

  const int tid = threadIdx.x;
  const int lane = tid & 63;
  const int wid = tid >> 6;
  const int wm = wid >> 1, wn = wid & 1;     // 4m x 2n
  const int q = lane >> 4, c = lane & 15;

  if (tid < 256) {
    int r = mt * 256 + tid;
    if (r >= cnt) r = cnt - 1;
    sTok[tid] = rows[base + r];
  }
  __syncthreads();

  // staging: 1KB chunk = 8 rows x 64 k (bf16); lane l -> row +(l>>3), src col pre-swizzled
  const int l8 = lane >> 3;
  const int colSw = ((lane & 7) ^ l8) << 3;  // in ushorts
  const unsigned short* ap[4];
  #pragma unroll
  for (int i = 0; i < 4; i++) {
    int row = wid * 32 + i * 8 + l8;
    ap[i] = Xbf + (size_t)(sTok[row] >> 1) * DDIM + colSw;
  }
  const unsigned short* gp[2];
  const unsigned short* up[2];
  #pragma unroll
  for (int i = 0; i < 2; i++) {
    int col = nt * 128 + wid * 16 + i * 8 + l8;
    gp[i] = WgT + ((size_t)e * FDIM + col) * DDIM + colSw;
    up[i] = WuT + ((size_t)e * FDIM + col) * DDIM + colSw;
  }

  f32x4 accg[4][4], accu[4][4];
  #pragma unroll
  for (int i = 0; i < 4; i++)
    #pragma unroll
    for (int j = 0; j < 4; j++) { accg[i][j] = (f32x4)(0.f); accu[i][j] = (f32x4)(0.f); }

  #define GU_STAGE(kt_, b_) do {                                          \
    const int ko_ = (kt_) * 64;                                           \
    _Pragma("unroll")                                                     \
    for (int i_ = 0; i_ < 4; i_++)                                        \
      gld16(ap[i_] + ko_, sA[b_] + wid * 4096 + i_ * 1024);               \
    _Pragma("unroll")                                                     \
    for (int i_ = 0; i_ < 2; i_++) {                                      \
      gld16(gp[i_] + ko_, sBg[b_] + wid * 2048 + i_ * 1024);              \
      gld16(up[i_] + ko_, sBu[b_] + wid * 2048 + i_ * 1024);              \
    }                                                                     \
  } while (0)

  const int NT = DDIM / 64;                  // 16
  GU_STAGE(0, 0);

  int cur = 0;
  for (int kt = 0; kt < NT; kt++) {
    asm volatile("s_barrier" ::: "memory");            // all reads of buf cur^1 done
    if (kt + 1 < NT) {
      GU_STAGE(kt + 1, cur ^ 1);
      asm volatile("s_waitcnt vmcnt(8)\n\ts_barrier" ::: "memory");  // stage(kt) ready
    } else {
      asm volatile("s_waitcnt vmcnt(0)\n\ts_barrier" ::: "memory");
    }
    const unsigned char* bA = sA[cur];
    const unsigned char* bG = sBg[cur];
    const unsigned char* bU = sBu[cur];
    __builtin_amdgcn_s_setprio(1);
    #pragma unroll
    for (int kk = 0; kk < 2; kk++) {
      short8 af[4];
      #pragma unroll
      for (int mf = 0; mf < 4; mf++) {
        int row = wm * 64 + mf * 16 + c;
        af[mf] = *(const short8*)(bA + ((row * 128 + kk * 64 + q * 16) ^ ((row & 7) << 4)));
      }
      #pragma unroll
      for (int nf = 0; nf < 4; nf++) {
        int col = wn * 64 + nf * 16 + c;
        int b = (col * 128 + kk * 64 + q * 16) ^ ((col & 7) << 4);
        short8 bg = *(const short8*)(bG + b);
        short8 bu = *(const short8*)(bU + b);
        #pragma unroll
        for (int mf = 0; mf < 4; mf++) {
          accg[mf][nf] = __builtin_amdgcn_mfma_f32_16x16x32_bf16(af[mf], bg, accg[mf][nf], 0, 0, 0);
          accu[mf][nf] = __builtin_amdgcn_mfma_f32_16x16x32_bf16(af[mf], bu, accu[mf][nf], 0, 0, 0);
        }
      }
    }
    __builtin_amdgcn_s_setprio(0);
    cur ^= 1;
  }

  #pragma unroll
  for (int mf = 0; mf < 4; mf++)
    #pragma unroll
    for (int nf = 0; nf < 4; nf++)
      #pragma unroll
      for (int r = 0; r < 4; r++) {
        int row = wm * 64 + mf * 16 + q * 4 + r;
        int gr = mt * 256 + row;
        if (gr < cnt) {
          int col = wn * 64 + nf * 16 + c;
          float g = accg[mf][nf][r], u = accu[mf][nf][r];
          float sv = g / (1.0f + __expf(-g));
          H[(size_t)(base + gr) * FDIM + nt * 128 + col] = f2bf(sv * u);
        }
      }
}

// ---------------- 5. down grouped GEMM ----------------
// tile 256(M) x 256(N of D) x 64(K of F); 8 waves (4m x 2n); wave tile 64x128.
// MODE 0: store bf16 O;  MODE 1: weighted atomicAdd into out (out pre-zeroed)
template <int MODE>
__global__ __launch_bounds__(512) void k_down(
    const unsigned short* __restrict__ H, const unsigned short* __restrict__ WdT,
    const int* __restrict__ counts, const int* __restrict__ offsets,
    const int* __restrict__ rows, const float* __restrict__ topk_w,
    unsigned short* __restrict__ O, float* __restrict__ out)
{
  const int id = blockIdx.x;
  const int xcd = id & 7;
  const int within = id >> 3;                // 0..63
  const int e = xcd * 2 + (within >= 32);
  const int rem = within & 31;               // 0..31
  const int mt = rem >> 2;                   // 0..7
  const int nt = rem & 3;                    // 0..3

  const int cnt = counts[e];
  if (mt * 256 >= cnt) return;
  const int base = offsets[e];

  __shared__ __align__(16) unsigned char sA[2][256 * 64 * 2];   // 32KB x2
  __shared__ __align__(16) unsigned char sB[2][256 * 64 * 2];   // 32KB x2
  __shared__ int sTk[256];
  __shared__ float sW[256];

  const int tid = threadIdx.x;
  const int lane = tid & 63;
  const int wid = tid >> 6;
  const int wm = wid >> 1, wn = wid & 1;
  const int q = lane >> 4, c = lane & 15;

  if (MODE == 1 && tid < 256) {
    int r = mt * 256 + tid;
    if (r >= cnt) r = cnt - 1;
    int s = rows[base + r];
    sTk[tid] = s >> 1;
    sW[tid] = topk_w[s];
  }
  if (MODE == 1) __syncthreads();

  const int l8 = lane >> 3;
  const int colSw = ((lane & 7) ^ l8) << 3;  // ushorts
  const unsigned short* ap[4];
  const unsigned short* bp[4];
  #pragma unroll
  for (int i = 0; i < 4; i++) {
    int row = wid * 32 + i * 8 + l8;
    int ga = base + mt * 256 + row; if (ga > NSLOT - 1) ga = NSLOT - 1;
    ap[i] = H + (size_t)ga * FDIM + colSw;
    int col = nt * 256 + row;
    bp[i] = WdT + ((size_t)e * DDIM + col) * FDIM + colSw;
  }

  f32x4 acc[4][8];
  #pragma unroll
  for (int i = 0; i < 4; i++)
    #pragma unroll
    for (int j = 0; j < 8; j++) acc[i][j] = (f32x4)(0.f);

  #define DN_STAGE(kt_, b_) do {                                          \
    const int ko_ = (kt_) * 64;                                           \
    _Pragma("unroll")                                                     \
    for (int i_ = 0; i_ < 4; i_++) {                                      \
      gld16(ap[i_] + ko_, sA[b_] + wid * 4096 + i_ * 1024);               \
      gld16(bp[i_] + ko_, sB[b_] + wid * 4096 + i_ * 1024);               \
    }                                                                     \
  } while (0)

  const int NT = FDIM / 64;                  // 12
  DN_STAGE(0, 0);

  int cur = 0;
  for (int kt = 0; kt < NT; kt++) {
    asm volatile("s_barrier" ::: "memory");
    if (kt + 1 < NT) {
      DN_STAGE(kt + 1, cur ^ 1);
      asm volatile("s_waitcnt vmcnt(8)\n\ts_barrier" ::: "memory");
    } else {
      asm volatile("s_waitcnt vmcnt(0)\n\ts_barrier" ::: "memory");
    }
    const unsigned char* bA = sA[cur];
    const unsigned char* bB = sB[cur];
    __builtin_amdgcn_s_setprio(1);
    #pragma unroll
    for (int kk = 0; kk < 2; kk++) {
      short8 af[4];
      #pragma unroll
      for (int mf = 0; mf < 4; mf++) {
        int row = wm * 64 + mf * 16 + c;
        af[mf] = *(const short8*)(bA + ((row * 128 + kk * 64 + q * 16) ^ ((row & 7) << 4)));
      }
      #pragma unroll
      for (int nf = 0; nf < 8; nf++) {
        int col = wn * 128 + nf * 16 + c;
        short8 bf = *(const short8*)(bB + ((col * 128 + kk * 64 + q * 16) ^ ((col & 7) << 4)));
        #pragma unroll
        for (int mf = 0; mf < 4; mf++)
          acc[mf][nf] = __builtin_amdgcn_mfma_f32_16x16x32_bf16(af[mf], bf, acc[mf][nf], 0, 0, 0);
      }
    }
    __builtin_amdgcn_s_setprio(0);
    cur ^= 1;
  }

  #pragma unroll
  for (int mf = 0; mf < 4; mf++)
    #pragma unroll
    for (int nf = 0; nf < 8; nf++)
      #pragma unroll
      for (int r = 0; r < 4; r++) {
        int row = wm * 64 + mf * 16 + q * 4 + r;
        int gr = mt * 256 + row;
        if (gr < cnt) {
          int col = wn * 128 + nf * 16 + c;
          if (MODE == 0) {
            O[(size_t)(base + gr) * DDIM + nt * 256 + col] = f2bf(acc[mf][nf][r]);
          } else {
            atomicAdd(&out[(size_t)sTk[row] * DDIM + nt * 256 + col], sW[row] * acc[mf][nf][r]);
          }
        }
      }
}

// ---------------- 6. combine top-2 (MODE 0 only) ----------------
__global__ __launch_bounds__(128) void k_combine(
    const unsigned short* __restrict__ O, const int* __restrict__ row_of,
    const float* __restrict__ topk_w, float* __restrict__ out)
{
  int t = blockIdx.x;
  int r0 = row_of[2 * t], r1 = row_of[2 * t + 1];
  float w0 = topk_w[2 * t], w1 = topk_w[2 * t + 1];
  int d = threadIdx.x * 8;
  short8 a = *(const short8*)(O + (size_t)r0 * DDIM + d);
  short8 b = *(const short8*)(O + (size_t)r1 * DDIM + d);
  float4 o0, o1;
  #pragma unroll
  for (int j = 0; j < 8; j++) {
    float r = w0 * bf2f((unsigned short)a[j]) + w1 * bf2f((unsigned short)b[j]);
    if (j < 4) ((float*)&o0)[j] = r; else ((float*)&o1)[j - 4] = r;
  }
  *(float4*)(out + (size_t)t * DDIM + d) = o0;
  *(float4*)(out + (size_t)t * DDIM + d + 4) = o1;
}

// ---------------- 7. aux loss ----------------
__global__ void k_aux(const int* __restrict__ counts, const float* __restrict__ prob_sum,
                      float* __restrict__ out_aux) {
  if (threadIdx.x == 0) {
    float s = 0.f;
    for (int e = 0; e < ENUM; e++)
      s += ((float)counts[e] / (float)NTOK) * (prob_sum[e] / (float)NTOK);
    out_aux[0] = 0.001f * (float)ENUM * s;
  }
}

extern "C" void kernel_launch(void* const* d_in, const int* in_sizes, int n_in,
                              void* d_out, int out_size, void* d_ws, size_t ws_size,
                              hipStream_t stream) {
  const float* X  = (const float*)d_in[0];
  const float* Wg = (const float*)d_in[1];
  const float* Wu = (const float*)d_in[2];
  const float* Wd = (const float*)d_in[3];
  const float* Wr = (const float*)d_in[4];
  float* out = (float*)d_out;

  char* ws = (char*)d_ws;
  int*   topk_idx = (int*)(ws + WS_TOPK_IDX);
  float* topk_w   = (float*)(ws + WS_TOPK_W);
  int*   rows     = (int*)(ws + WS_ROWS);
  int*   row_of   = (int*)(ws + WS_ROW_OF);
  int*   counts   = (int*)(ws + WS_COUNTS);
  float* prob_sum = (float*)(ws + WS_PROB);
  int*   offsets  = (int*)(ws + WS_OFFSETS);
  unsigned short* Xbf = (unsigned short*)(ws + WS_XBF);
  unsigned short* H   = (unsigned short*)(ws + WS_H);
  unsigned short* WgT = (unsigned short*)(ws + WS_WGT);
  unsigned short* WuT = (unsigned short*)(ws + WS_WUT);
  unsigned short* WdT = (unsigned short*)(ws + WS_WDT);
  unsigned short* O   = (unsigned short*)(ws + WS_O);

  const bool useO = (ws_size >= WS_NEED_O);

  hipMemsetAsync(ws + WS_COUNTS, 0, 128, stream);
  if (!useO) hipMemsetAsync(d_out, 0, (size_t)out_size * 4, stream);

  k_convert_x<<<8192, 256, 0, stream>>>(X, Xbf);
  k_wt<<<dim3(FDIM / 64, DDIM / 64, ENUM), 256, 0, stream>>>(Wg, WgT, DDIM, FDIM);
  k_wt<<<dim3(FDIM / 64, DDIM / 64, ENUM), 256, 0, stream>>>(Wu, WuT, DDIM, FDIM);
  k_wt<<<dim3(DDIM / 64, FDIM / 64, ENUM), 256, 0, stream>>>(Wd, WdT, FDIM, DDIM);
  k_router<<<512, 256, 0, stream>>>(X, Wr, topk_idx, topk_w, counts, prob_sum);
  k_build_lists<<<16, 256, 0, stream>>>(topk_idx, counts, offsets, rows, row_of);
  k_gateup<<<768, 512, 0, stream>>>(Xbf, WgT, WuT, counts, offsets, rows, H);
  if (useO) {
    k_down<0><<<512, 512, 0, stream>>>(H, WdT, counts, offsets, rows, topk_w, O, out);
    k_combine<<<8192, 128, 0, stream>>>(O, row_of, topk_w, out);
  } else {
    k_down<1><<<512, 512, 0, stream>>>(H, WdT, counts, offsets, rows, topk_w, O, out);
  }
  k_aux<<<1, 64, 0, stream>>>(counts, prob_sum, out + (size_t)NTOK * DDIM);
}

// Round 6
// 255.611 us; speedup vs baseline: 1.2083x; 1.1413x over previous
//
#include <hip/hip_runtime.h>

typedef __attribute__((ext_vector_type(8))) short short8;
typedef __attribute__((ext_vector_type(4))) float f32x4;

#define NTOK   8192
#define DDIM   1024
#define ENUM   16
#define FDIM   768
#define NSLOT  16384

// ---------- ws layout (bytes) ----------
#define WS_TOPK_IDX 0           // int[16384]
#define WS_TOPK_W   65536       // float[16384]
#define WS_ROWS     131072      // int[16384]
#define WS_ROW_OF   196608      // int[16384]
#define WS_COUNTS   262144      // int[16]
#define WS_PROB     262208      // float[16]
#define WS_OFFSETS  262272      // int[17]
#define WS_XBF      1048576ull                      // bf16[8192][1024]   16 MB
#define WS_H        (WS_XBF + 16777216ull)          // bf16[16384][768]   24 MB
#define WS_WGT      (WS_H + 25165824ull)            // bf16[E][F][D]      24 MB
#define WS_WUT      (WS_WGT + 25165824ull)          // bf16[E][F][D]      24 MB
#define WS_WDT      (WS_WUT + 25165824ull)          // bf16[E][D][F]      24 MB
#define WS_O        (WS_WDT + 25165824ull)          // bf16[16384][1024]  32 MB (optional)
#define WS_NEED_O   (WS_O + 33554432ull)

__device__ __forceinline__ unsigned short f2bf(float f) {
  union { float f; unsigned int u; } v; v.f = f;
  unsigned int r = v.u + 0x7fffu + ((v.u >> 16) & 1u);
  return (unsigned short)(r >> 16);
}
__device__ __forceinline__ float bf2f(unsigned short s) {
  union { unsigned int u; float f; } v; v.u = ((unsigned int)s) << 16;
  return v.f;
}

__device__ __forceinline__ void gld16(const void* g, void* l) {
  __builtin_amdgcn_global_load_lds((const __attribute__((address_space(1))) unsigned int*)g,
                                   (__attribute__((address_space(3))) unsigned int*)l, 16, 0, 0);
}

// ---------------- 1. hidden fp32 -> bf16 ----------------
__global__ void k_convert_x(const float* __restrict__ x, unsigned short* __restrict__ xb) {
  int i = blockIdx.x * blockDim.x + threadIdx.x;
  float4 v = ((const float4*)x)[i];
  ushort4 o;
  o.x = f2bf(v.x); o.y = f2bf(v.y); o.z = f2bf(v.z); o.w = f2bf(v.w);
  ((ushort4*)xb)[i] = o;
}

// ---------------- 1b. weight transpose+convert, all 3 matrices in one launch ----------------
// z<16: Wg (R=D,C=F); z<32: Wu; z>=32: Wd (R=F,C=D). WT[e][c][r] = bf16(W[e][r][c])
__global__ __launch_bounds__(256) void k_wt_all(
    const float* __restrict__ Wg, const float* __restrict__ Wu, const float* __restrict__ Wd,
    unsigned short* __restrict__ WgT, unsigned short* __restrict__ WuT, unsigned short* __restrict__ WdT)
{
  int z = blockIdx.z;
  const float* W; unsigned short* WT; int R, C, e;
  if (z < 16)      { W = Wg; WT = WgT; R = DDIM; C = FDIM; e = z; }
  else if (z < 32) { W = Wu; WT = WuT; R = DDIM; C = FDIM; e = z - 16; }
  else             { W = Wd; WT = WdT; R = FDIM; C = DDIM; e = z - 32; }
  int r0 = blockIdx.y * 64, c0 = blockIdx.x * 64;
  if (r0 >= R || c0 >= C) return;

  __shared__ float t[64][68];
  int tid = threadIdx.x;
  int rr = tid >> 2, cc = (tid & 3) * 16;
  const float* src = W + (size_t)e * R * C + (size_t)(r0 + rr) * C + c0 + cc;
  float4 v0 = *(const float4*)(src);
  float4 v1 = *(const float4*)(src + 4);
  float4 v2 = *(const float4*)(src + 8);
  float4 v3 = *(const float4*)(src + 12);
  *(float4*)&t[rr][cc]      = v0;
  *(float4*)&t[rr][cc + 4]  = v1;
  *(float4*)&t[rr][cc + 8]  = v2;
  *(float4*)&t[rr][cc + 12] = v3;
  __syncthreads();
  int fr = tid >> 2, dd = (tid & 3) * 16;
  union { unsigned short s[16]; uint4 v[2]; } o;
  #pragma unroll
  for (int j = 0; j < 16; j++) o.s[j] = f2bf(t[dd + j][fr]);
  unsigned short* dst = WT + (size_t)e * C * R + (size_t)(c0 + fr) * R + r0 + dd;
  *(uint4*)dst = o.v[0];
  *((uint4*)dst + 1) = o.v[1];
}

// ---------------- 2. router ----------------
__global__ __launch_bounds__(256) void k_router(
    const float* __restrict__ X, const float* __restrict__ Wr,
    int* __restrict__ topk_idx, float* __restrict__ topk_w,
    int* __restrict__ counts, float* __restrict__ prob_sum)
{
  int tid = threadIdx.x, lane = tid & 63, wid = tid >> 6;
  int wave_global = blockIdx.x * 4 + wid;
  int q = lane >> 4, e = lane & 15;
  float pacc = 0.f; int cacc = 0;

  for (int i = 0; i < 4; i++) {
    int t = wave_global * 4 + i;
    const float* x = X + (size_t)t * DDIM + q * 256;
    const float* w = Wr + q * 256 * ENUM + e;
    double a0 = 0.0, a1 = 0.0;
    #pragma unroll 4
    for (int j = 0; j < 256; j += 2) {
      a0 += (double)x[j] * (double)w[j * ENUM];
      a1 += (double)x[j + 1] * (double)w[(j + 1) * ENUM];
    }
    double acc = a0 + a1;
    acc += __shfl_xor(acc, 16, 64);
    acc += __shfl_xor(acc, 32, 64);
    float logit = (float)acc;

    float m = logit;
    for (int d = 1; d < 16; d <<= 1) m = fmaxf(m, __shfl_xor(m, d, 64));
    float p = expf(logit - m);
    float s = p;
    for (int d = 1; d < 16; d <<= 1) s += __shfl_xor(s, d, 64);
    p = p / s;

    float p1 = p; int e1 = e;
    for (int d = 1; d < 16; d <<= 1) {
      float op = __shfl_xor(p1, d, 64); int oe = __shfl_xor(e1, d, 64);
      if (op > p1 || (op == p1 && oe < e1)) { p1 = op; e1 = oe; }
    }
    float px = (e == e1) ? -1.f : p;
    float p2 = px; int e2 = e;
    for (int d = 1; d < 16; d <<= 1) {
      float op = __shfl_xor(p2, d, 64); int oe = __shfl_xor(e2, d, 64);
      if (op > p2 || (op == p2 && oe < e2)) { p2 = op; e2 = oe; }
    }
    float den = fmaxf(p1 + p2, 1e-9f);
    if (lane == 0) {
      topk_idx[2 * t]     = e1; topk_idx[2 * t + 1] = e2;
      topk_w[2 * t]       = p1 / den; topk_w[2 * t + 1] = p2 / den;
    }
    if (lane < 16) { pacc += p; cacc += (e1 == e) + (e2 == e); }
  }
  __shared__ float sp[16]; __shared__ int sc[16];
  if (tid < 16) { sp[tid] = 0.f; sc[tid] = 0; }
  __syncthreads();
  if (lane < 16) { atomicAdd(&sp[e], pacc); atomicAdd(&sc[e], cacc); }
  __syncthreads();
  if (tid < 16) { atomicAdd(&prob_sum[tid], sp[tid]); atomicAdd(&counts[tid], sc[tid]); }
}

// ---------------- 3. deterministic per-expert slot lists (1024 thr: 16 chunks) ----------------
__global__ __launch_bounds__(1024) void k_build_lists(
    const int* __restrict__ topk_idx, const int* __restrict__ counts,
    int* __restrict__ offsets, int* __restrict__ rows, int* __restrict__ row_of)
{
  int e = blockIdx.x;
  int base = 0;
  for (int i = 0; i < e; i++) base += counts[i];
  if (threadIdx.x == 0) {
    offsets[e] = base;
    if (e == 15) offsets[16] = base + counts[15];
  }
  __shared__ int wave_tot[16];
  int lane = threadIdx.x & 63, wid = threadIdx.x >> 6;
  int running = 0;
  for (int chunk = 0; chunk < NSLOT; chunk += 1024) {
    int s = chunk + threadIdx.x;
    bool match = (topk_idx[s] == e);
    unsigned long long mask = __ballot(match);
    int wpre = __popcll(mask & ((1ull << lane) - 1ull));
    if (lane == 0) wave_tot[wid] = __popcll(mask);
    __syncthreads();
    int prefix = running;
    for (int w = 0; w < wid; w++) prefix += wave_tot[w];
    if (match) { int pos = base + prefix + wpre; rows[pos] = s; row_of[s] = pos; }
    int tot = 0;
    for (int w = 0; w < 16; w++) tot += wave_tot[w];
    running += tot;
    __syncthreads();
  }
}

// ---------------- 4. fused gate+up grouped GEMM ----------------
// tile 256(M) x 128(N of F) x 64(K); 8 waves (4m x 2n); wave tile 64x64.
// 4-phase interleaved K-step: phase=(kk, n-half) = {ds_reads | stage gld16 | barrier | 16 MFMA}
__global__ __launch_bounds__(512) void k_gateup(
    const unsigned short* __restrict__ Xbf, const unsigned short* __restrict__ WgT,
    const unsigned short* __restrict__ WuT, const int* __restrict__ counts,
    const int* __restrict__ offsets, const int* __restrict__ rows,
    unsigned short* __restrict__ H)
{
  const int id = blockIdx.x;
  const int xcd = id & 7;
  const int within = id >> 3;                // 0..95
  const int e = xcd * 2 + (within >= 48);
  const int rem = within - (within >= 48 ? 48 : 0);  // 0..47
  const int mt = rem / 6;                    // 0..7
  const int nt = rem - mt * 6;               // 0..5

  const int cnt = counts[e];
  if (mt * 256 >= cnt) return;
  const int base = offsets[e];

  __shared__ __align__(16) unsigned char sA [2][256 * 64 * 2];  // 32KB x2
  __shared__ __align__(16) unsigned char sBg[2][128 * 64 * 2];  // 16KB x2
  __shared__ __align__(16) unsigned char sBu[2][128 * 64 * 2];  // 16KB x2
  __shared__ int sTok[256];

  const int tid = threadIdx.x;
  const int lane = tid & 63;
  const int wid = tid >> 6;
  const int wm = wid >> 1, wn = wid & 1;     // 4m x 2n
  const int q = lane >> 4, c = lane & 15;

  if (tid < 256) {
    int r = mt * 256 + tid;
    if (r >= cnt) r = cnt - 1;
    sTok[tid] = rows[base + r];
  }
  __syncthreads();

  // staging: 1KB chunk = 8 rows x 64 k (bf16); lane l -> row +(l>>3), src col pre-swizzled
  const int l8 = lane >> 3;
  const int colSw = ((lane & 7) ^ l8) << 3;  // in ushorts
  const unsigned short* ap[4];
  #pragma unroll
  for (int i = 0; i < 4; i++) {
    int row = wid * 32 + i * 8 + l8;
    ap[i] = Xbf + (size_t)(sTok[row] >> 1) * DDIM + colSw;
  }
  const unsigned short* gp[2];
  const unsigned short* up[2];
  #pragma unroll
  for (int i = 0; i < 2; i++) {
    int col = nt * 128 + wid * 16 + i * 8 + l8;
    gp[i] = WgT + ((size_t)e * FDIM + col) * DDIM + colSw;
    up[i] = WuT + ((size_t)e * FDIM + col) * DDIM + colSw;
  }

  f32x4 accg[4][4], accu[4][4];
  #pragma unroll
  for (int i = 0; i < 4; i++)
    #pragma unroll
    for (int j = 0; j < 4; j++) { accg[i][j] = (f32x4)(0.f); accu[i][j] = (f32x4)(0.f); }

  const int NT = DDIM / 64;                  // 16

  // prologue: full stage of kt=0 into buf 0
  {
    #pragma unroll
    for (int i = 0; i < 4; i++) gld16(ap[i], sA[0] + wid * 4096 + i * 1024);
    #pragma unroll
    for (int i = 0; i < 2; i++) {
      gld16(gp[i], sBg[0] + wid * 2048 + i * 1024);
      gld16(up[i], sBu[0] + wid * 2048 + i * 1024);
    }
  }
  asm volatile("s_waitcnt vmcnt(0)" ::: "memory");
  __builtin_amdgcn_s_barrier();

  int cur = 0;
  for (int kt = 0; kt < NT; kt++) {
    const unsigned char* bA = sA[cur];
    const unsigned char* bG = sBg[cur];
    const unsigned char* bU = sBu[cur];
    const int stage = (kt + 1 < NT);
    const int ko = (kt + 1) * 64;
    short8 af[4];
    #pragma unroll
    for (int ph = 0; ph < 4; ph++) {
      const int kk = ph >> 1, h = ph & 1;
      // ---- ds reads for this phase ----
      if (h == 0) {
        #pragma unroll
        for (int mf = 0; mf < 4; mf++) {
          int row = wm * 64 + mf * 16 + c;
          af[mf] = *(const short8*)(bA + ((row * 128 + kk * 64 + q * 16) ^ ((row & 7) << 4)));
        }
      }
      short8 bg[2], bu[2];
      #pragma unroll
      for (int j = 0; j < 2; j++) {
        int col = wn * 64 + (h * 2 + j) * 16 + c;
        int b = (col * 128 + kk * 64 + q * 16) ^ ((col & 7) << 4);
        bg[j] = *(const short8*)(bG + b);
        bu[j] = *(const short8*)(bU + b);
      }
      // ---- stage next tile (spread over phases 0-1) ----
      if (stage) {
        if (ph == 0) {
          #pragma unroll
          for (int i = 0; i < 4; i++) gld16(ap[i] + ko, sA[cur ^ 1] + wid * 4096 + i * 1024);
        } else if (ph == 1) {
          #pragma unroll
          for (int i = 0; i < 2; i++) {
            gld16(gp[i] + ko, sBg[cur ^ 1] + wid * 2048 + i * 1024);
            gld16(up[i] + ko, sBu[cur ^ 1] + wid * 2048 + i * 1024);
          }
        }
      }
      __builtin_amdgcn_s_barrier();          // lockstep: pipes interleave across waves
      __builtin_amdgcn_s_setprio(1);
      #pragma unroll
      for (int j = 0; j < 2; j++) {
        const int nf = h * 2 + j;
        #pragma unroll
        for (int mf = 0; mf < 4; mf++) {
          accg[mf][nf] = __builtin_amdgcn_mfma_f32_16x16x32_bf16(af[mf], bg[j], accg[mf][nf], 0, 0, 0);
          accu[mf][nf] = __builtin_amdgcn_mfma_f32_16x16x32_bf16(af[mf], bu[j], accu[mf][nf], 0, 0, 0);
        }
      }
      __builtin_amdgcn_s_setprio(0);
    }
    // iter boundary: own stage loads landed; publish to all waves
    asm volatile("s_waitcnt vmcnt(0)" ::: "memory");
    __builtin_amdgcn_s_barrier();
    cur ^= 1;
  }

  #pragma unroll
  for (int mf = 0; mf < 4; mf++)
    #pragma unroll
    for (int nf = 0; nf < 4; nf++)
      #pragma unroll
      for (int r = 0; r < 4; r++) {
        int row = wm * 64 + mf * 16 + q * 4 + r;
        int gr = mt * 256 + row;
        if (gr < cnt) {
          int col = wn * 64 + nf * 16 + c;
          float g = accg[mf][nf][r], u = accu[mf][nf][r];
          float sv = g / (1.0f + __expf(-g));
          H[(size_t)(base + gr) * FDIM + nt * 128 + col] = f2bf(sv * u);
        }
      }
}

// ---------------- 5. down grouped GEMM ----------------
// tile 256(M) x 256(N of D) x 64(K of F); 8 waves (4m x 2n); wave tile 64x128; 4-phase.
// MODE 0: store bf16 O;  MODE 1: weighted atomicAdd into out (out pre-zeroed)
template <int MODE>
__global__ __launch_bounds__(512) void k_down(
    const unsigned short* __restrict__ H, const unsigned short* __restrict__ WdT,
    const int* __restrict__ counts, const int* __restrict__ offsets,
    const int* __restrict__ rows, const float* __restrict__ topk_w,
    unsigned short* __restrict__ O, float* __restrict__ out)
{
  const int id = blockIdx.x;
  const int xcd = id & 7;
  const int within = id >> 3;                // 0..63
  const int e = xcd * 2 + (within >= 32);
  const int rem = within & 31;               // 0..31
  const int mt = rem >> 2;                   // 0..7
  const int nt = rem & 3;                    // 0..3

  const int cnt = counts[e];
  if (mt * 256 >= cnt) return;
  const int base = offsets[e];

  __shared__ __align__(16) unsigned char sA[2][256 * 64 * 2];   // 32KB x2
  __shared__ __align__(16) unsigned char sB[2][256 * 64 * 2];   // 32KB x2
  __shared__ int sTk[256];
  __shared__ float sW[256];

  const int tid = threadIdx.x;
  const int lane = tid & 63;
  const int wid = tid >> 6;
  const int wm = wid >> 1, wn = wid & 1;
  const int q = lane >> 4, c = lane & 15;

  if (MODE == 1 && tid < 256) {
    int r = mt * 256 + tid;
    if (r >= cnt) r = cnt - 1;
    int s = rows[base + r];
    sTk[tid] = s >> 1;
    sW[tid] = topk_w[s];
  }
  if (MODE == 1) __syncthreads();

  const int l8 = lane >> 3;
  const int colSw = ((lane & 7) ^ l8) << 3;  // ushorts
  const unsigned short* ap[4];
  const unsigned short* bp[4];
  #pragma unroll
  for (int i = 0; i < 4; i++) {
    int row = wid * 32 + i * 8 + l8;
    int ga = base + mt * 256 + row; if (ga > NSLOT - 1) ga = NSLOT - 1;
    ap[i] = H + (size_t)ga * FDIM + colSw;
    int col = nt * 256 + row;
    bp[i] = WdT + ((size_t)e * DDIM + col) * FDIM + colSw;
  }

  f32x4 acc[4][8];
  #pragma unroll
  for (int i = 0; i < 4; i++)
    #pragma unroll
    for (int j = 0; j < 8; j++) acc[i][j] = (f32x4)(0.f);

  const int NT = FDIM / 64;                  // 12

  {
    #pragma unroll
    for (int i = 0; i < 4; i++) {
      gld16(ap[i], sA[0] + wid * 4096 + i * 1024);
      gld16(bp[i], sB[0] + wid * 4096 + i * 1024);
    }
  }
  asm volatile("s_waitcnt vmcnt(0)" ::: "memory");
  __builtin_amdgcn_s_barrier();

  int cur = 0;
  for (int kt = 0; kt < NT; kt++) {
    const unsigned char* bA = sA[cur];
    const unsigned char* bB = sB[cur];
    const int stage = (kt + 1 < NT);
    const int ko = (kt + 1) * 64;
    short8 af[4];
    #pragma unroll
    for (int ph = 0; ph < 4; ph++) {
      const int kk = ph >> 1, h = ph & 1;
      if (h == 0) {
        #pragma unroll
        for (int mf = 0; mf < 4; mf++) {
          int row = wm * 64 + mf * 16 + c;
          af[mf] = *(const short8*)(bA + ((row * 128 + kk * 64 + q * 16) ^ ((row & 7) << 4)));
        }
      }
      short8 bf[4];
      #pragma unroll
      for (int j = 0; j < 4; j++) {
        int col = wn * 128 + (h * 4 + j) * 16 + c;
        bf[j] = *(const short8*)(bB + ((col * 128 + kk * 64 + q * 16) ^ ((col & 7) << 4)));
      }
      if (stage) {
        if (ph == 0) {
          #pragma unroll
          for (int i = 0; i < 4; i++) gld16(ap[i] + ko, sA[cur ^ 1] + wid * 4096 + i * 1024);
        } else if (ph == 1) {
          #pragma unroll
          for (int i = 0; i < 4; i++) gld16(bp[i] + ko, sB[cur ^ 1] + wid * 4096 + i * 1024);
        }
      }
      __builtin_amdgcn_s_barrier();
      __builtin_amdgcn_s_setprio(1);
      #pragma unroll
      for (int j = 0; j < 4; j++) {
        const int nf = h * 4 + j;
        #pragma unroll
        for (int mf = 0; mf < 4; mf++)
          acc[mf][nf] = __builtin_amdgcn_mfma_f32_16x16x32_bf16(af[mf], bf[j], acc[mf][nf], 0, 0, 0);
      }
      __builtin_amdgcn_s_setprio(0);
    }
    asm volatile("s_waitcnt vmcnt(0)" ::: "memory");
    __builtin_amdgcn_s_barrier();
    cur ^= 1;
  }

  #pragma unroll
  for (int mf = 0; mf < 4; mf++)
    #pragma unroll
    for (int nf = 0; nf < 8; nf++)
      #pragma unroll
      for (int r = 0; r < 4; r++) {
        int row = wm * 64 + mf * 16 + q * 4 + r;
        int gr = mt * 256 + row;
        if (gr < cnt) {
          int col = wn * 128 + nf * 16 + c;
          if (MODE == 0) {
            O[(size_t)(base + gr) * DDIM + nt * 256 + col] = f2bf(acc[mf][nf][r]);
          } else {
            atomicAdd(&out[(size_t)sTk[row] * DDIM + nt * 256 + col], sW[row] * acc[mf][nf][r]);
          }
        }
      }
}

// ---------------- 6. combine top-2 (MODE 0 only) ----------------
__global__ __launch_bounds__(128) void k_combine(
    const unsigned short* __restrict__ O, const int* __restrict__ row_of,
    const float* __restrict__ topk_w, float* __restrict__ out)
{
  int t = blockIdx.x;
  int r0 = row_of[2 * t], r1 = row_of[2 * t + 1];
  float w0 = topk_w[2 * t], w1 = topk_w[2 * t + 1];
  int d = threadIdx.x * 8;
  short8 a = *(const short8*)(O + (size_t)r0 * DDIM + d);
  short8 b = *(const short8*)(O + (size_t)r1 * DDIM + d);
  float4 o0, o1;
  #pragma unroll
  for (int j = 0; j < 8; j++) {
    float r = w0 * bf2f((unsigned short)a[j]) + w1 * bf2f((unsigned short)b[j]);
    if (j < 4) ((float*)&o0)[j] = r; else ((float*)&o1)[j - 4] = r;
  }
  *(float4*)(out + (size_t)t * DDIM + d) = o0;
  *(float4*)(out + (size_t)t * DDIM + d + 4) = o1;
}

// ---------------- 7. aux loss ----------------
__global__ void k_aux(const int* __restrict__ counts, const float* __restrict__ prob_sum,
                      float* __restrict__ out_aux) {
  if (threadIdx.x == 0) {
    float s = 0.f;
    for (int e = 0; e < ENUM; e++)
      s += ((float)counts[e] / (float)NTOK) * (prob_sum[e] / (float)NTOK);
    out_aux[0] = 0.001f * (float)ENUM * s;
  }
}

extern "C" void kernel_launch(void* const* d_in, const int* in_sizes, int n_in,
                              void* d_out, int out_size, void* d_ws, size_t ws_size,
                              hipStream_t stream) {
  const float* X  = (const float*)d_in[0];
  const float* Wg = (const float*)d_in[1];
  const float* Wu = (const float*)d_in[2];
  const float* Wd = (const float*)d_in[3];
  const float* Wr = (const float*)d_in[4];
  float* out = (float*)d_out;

  char* ws = (char*)d_ws;
  int*   topk_idx = (int*)(ws + WS_TOPK_IDX);
  float* topk_w   = (float*)(ws + WS_TOPK_W);
  int*   rows     = (int*)(ws + WS_ROWS);
  int*   row_of   = (int*)(ws + WS_ROW_OF);
  int*   counts   = (int*)(ws + WS_COUNTS);
  float* prob_sum = (float*)(ws + WS_PROB);
  int*   offsets  = (int*)(ws + WS_OFFSETS);
  unsigned short* Xbf = (unsigned short*)(ws + WS_XBF);
  unsigned short* H   = (unsigned short*)(ws + WS_H);
  unsigned short* WgT = (unsigned short*)(ws + WS_WGT);
  unsigned short* WuT = (unsigned short*)(ws + WS_WUT);
  unsigned short* WdT = (unsigned short*)(ws + WS_WDT);
  unsigned short* O   = (unsigned short*)(ws + WS_O);

  const bool useO = (ws_size >= WS_NEED_O);

  hipMemsetAsync(ws + WS_COUNTS, 0, 128, stream);
  if (!useO) hipMemsetAsync(d_out, 0, (size_t)out_size * 4, stream);

  k_convert_x<<<8192, 256, 0, stream>>>(X, Xbf);
  k_wt_all<<<dim3(16, 16, 48), 256, 0, stream>>>(Wg, Wu, Wd, WgT, WuT, WdT);
  k_router<<<512, 256, 0, stream>>>(X, Wr, topk_idx, topk_w, counts, prob_sum);
  k_build_lists<<<16, 1024, 0, stream>>>(topk_idx, counts, offsets, rows, row_of);
  k_gateup<<<768, 512, 0, stream>>>(Xbf, WgT, WuT, counts, offsets, rows, H);
  if (useO) {
    k_down<0><<<512, 512, 0, stream>>>(H, WdT, counts, offsets, rows, topk_w, O, out);
    k_combine<<<8192, 128, 0, stream>>>(O, row_of, topk_w, out);
  } else {
    k_down<1><<<512, 512, 0, stream>>>(H, WdT, counts, offsets, rows, topk_w, O, out);
  }
  k_aux<<<1, 64, 0, stream>>>(counts, prob_sum, out + (size_t)NTOK * DDIM);
}